// Round 7
// baseline (246.243 us; speedup 1.0000x reference)
//
#include <hip/hip_runtime.h>

// LIF scan over T=8, N=4.2M float4-sites. Rounds 1-5 invariant: 2.2-2.3 TB/s.
// Root cause theory: LLVM's AMDGPU scheduler sinks hoisted loads to meet its
// max-occupancy register target, producing a synchronous per-wave schedule
// (burst load -> full vmcnt drain -> compute -> burst store, ~30% duty cycle
// of outstanding requests). Fix: __launch_bounds__(256, 2) relaxes the
// occupancy target to 2 waves/EU (256-VGPR budget) so the scheduler keeps all
// 8 loads in flight; spikes buffered in registers, all stores at the end
// (nontemporal so the 128 MiB output doesn't evict the L3-resident input).
// Round-6 fix: __builtin_nontemporal_store needs ext_vector_type, not HIP float4.

typedef float v4f __attribute__((ext_vector_type(4)));

#define DECAY  0.25f
#define THRESH 0.5f

__global__ __launch_bounds__(256, 2) void lif_scan_kernel(
    const v4f* __restrict__ x, v4f* __restrict__ out, int n4) {
    const int i = blockIdx.x * blockDim.x + threadIdx.x;
    if (i < n4) {
        const size_t idx = (size_t)i;
        const size_t st  = (size_t)n4;

        // 8 independent-address loads; with the relaxed occupancy target the
        // scheduler should keep all 8 outstanding.
        const v4f x0 = x[idx + 0 * st];
        const v4f x1 = x[idx + 1 * st];
        const v4f x2 = x[idx + 2 * st];
        const v4f x3 = x[idx + 3 * st];
        const v4f x4 = x[idx + 4 * st];
        const v4f x5 = x[idx + 5 * st];
        const v4f x6 = x[idx + 6 * st];
        const v4f x7 = x[idx + 7 * st];

        v4f m = {0.f, 0.f, 0.f, 0.f};
        v4f s = {0.f, 0.f, 0.f, 0.f};
        v4f sb[8];

        const v4f xv[8] = {x0, x1, x2, x3, x4, x5, x6, x7};
#pragma unroll
        for (int t = 0; t < 8; ++t) {
            m[0] = m[0] * (DECAY * (1.f - s[0])) + xv[t][0];
            m[1] = m[1] * (DECAY * (1.f - s[1])) + xv[t][1];
            m[2] = m[2] * (DECAY * (1.f - s[2])) + xv[t][2];
            m[3] = m[3] * (DECAY * (1.f - s[3])) + xv[t][3];
            s[0] = (m[0] >= THRESH) ? 1.f : 0.f;
            s[1] = (m[1] >= THRESH) ? 1.f : 0.f;
            s[2] = (m[2] >= THRESH) ? 1.f : 0.f;
            s[3] = (m[3] >= THRESH) ? 1.f : 0.f;
            sb[t] = s;
        }

        // All stores at the end, nontemporal: issue in one burst, drain in the
        // background, don't evict the L3-resident input.
#pragma unroll
        for (int t = 0; t < 8; ++t) {
            __builtin_nontemporal_store(sb[t], &out[idx + (size_t)t * st]);
        }
    }
}

extern "C" void kernel_launch(void* const* d_in, const int* in_sizes, int n_in,
                              void* d_out, int out_size, void* d_ws, size_t ws_size,
                              hipStream_t stream) {
    const float* x = (const float*)d_in[0];
    float* out = (float*)d_out;

    const int total = in_sizes[0];        // 8 * 32 * 128 * 32 * 32 = 33,554,432
    const int T = 8;
    const int n = total / T;              // 4,194,304 sites per timestep
    const int n4 = n / 4;                 // 1,048,576 float4 groups

    const int block = 256;
    const int grid = (n4 + block - 1) / block;  // 4096 blocks

    lif_scan_kernel<<<grid, block, 0, stream>>>(
        (const v4f*)x, (v4f*)out, n4);
}

// Round 8
// 230.239 us; speedup vs baseline: 1.0695x; 1.0695x over previous
//
#include <hip/hip_runtime.h>

// LIF scan over T=8, N=4.2M float4-sites. Rounds 1-7: seven different
// schedules (interleaved / hoisted / sched_barrier / 4-chain high-VGPR /
// asm vmcnt staircase / relaxed launch_bounds / NT stores) ALL land at
// 87-95 us, 2.2-2.3 TB/s TCC-visible. Round-4 had 64KB/CU of in-flight
// demand (3x the latency-BW product) and BW didn't move -> NOT an MLP /
// latency problem; the memory system's service rate for this pattern is the
// limit. Suspect: harness preconditioning (262 MiB dirty restore+poison in
// the 256 MiB MALL) causes invisible MALL->HBM forced writebacks billed to
// our kernel. This round: non-temporal LOADS + STORES (bypass MALL
// allocation both ways, force no evictions). Round-1 structure otherwise.

typedef float v4f __attribute__((ext_vector_type(4)));

#define DECAY  0.25f
#define THRESH 0.5f

__global__ __launch_bounds__(256) void lif_scan_kernel(
    const v4f* __restrict__ x, v4f* __restrict__ out, int n4) {
    const int i = blockIdx.x * blockDim.x + threadIdx.x;
    if (i >= n4) return;

    const size_t idx = (size_t)i;
    const size_t st  = (size_t)n4;

    v4f m = {0.f, 0.f, 0.f, 0.f};
    v4f s = {0.f, 0.f, 0.f, 0.f};

#pragma unroll
    for (int t = 0; t < 8; ++t) {
        const v4f xv = __builtin_nontemporal_load(&x[idx + (size_t)t * st]);
        m[0] = m[0] * (DECAY * (1.f - s[0])) + xv[0];
        m[1] = m[1] * (DECAY * (1.f - s[1])) + xv[1];
        m[2] = m[2] * (DECAY * (1.f - s[2])) + xv[2];
        m[3] = m[3] * (DECAY * (1.f - s[3])) + xv[3];
        s[0] = (m[0] >= THRESH) ? 1.f : 0.f;
        s[1] = (m[1] >= THRESH) ? 1.f : 0.f;
        s[2] = (m[2] >= THRESH) ? 1.f : 0.f;
        s[3] = (m[3] >= THRESH) ? 1.f : 0.f;
        __builtin_nontemporal_store(s, &out[idx + (size_t)t * st]);
    }
}

extern "C" void kernel_launch(void* const* d_in, const int* in_sizes, int n_in,
                              void* d_out, int out_size, void* d_ws, size_t ws_size,
                              hipStream_t stream) {
    const float* x = (const float*)d_in[0];
    float* out = (float*)d_out;

    const int total = in_sizes[0];        // 8 * 32 * 128 * 32 * 32 = 33,554,432
    const int T = 8;
    const int n = total / T;              // 4,194,304 sites per timestep
    const int n4 = n / 4;                 // 1,048,576 float4 groups

    const int block = 256;
    const int grid = (n4 + block - 1) / block;  // 4096 blocks

    lif_scan_kernel<<<grid, block, 0, stream>>>(
        (const v4f*)x, (v4f*)out, n4);
}